// Round 16
// baseline (15.689 us; speedup 1.0000x reference)
//
#include <hip/hip_runtime.h>
#include <math.h>

#define APAD 28          // padded row stride for 21-wide tiles
#define W1PAD 132        // padded row stride for 128-wide tiles

// ws float layout (acc zeroed by block 63 each launch; poison-safe):
#define WS_ACC1 0
#define WS_ACC2 512

// Reset-based sync state: all words are 0 at module load; every word is
// restored to 0 by a provably-safe owner before kernel end:
//   g_arrive[i]: block i self-resets after observing g_go==2 (leader's
//                phase-2 collection already done by then)
//   g_zr       : block 63 resets after bar1 release (release proves all
//                GCN blocks passed the gate)
//   g_go,g_seen: leader resets after all 63 others bump g_seen post-bar2
//                (happens while FC3 blocks still compute -> no added time)
__device__ unsigned g_arrive[64 * 16];   // 64B-strided arrival slots
__device__ unsigned g_go;                // barrier release word
__device__ unsigned g_zr;                // accumulators-zeroed flag
__device__ unsigned g_seen;              // post-bar2 confirmations (63)

// Agent-scope relaxed atomics: cache-bypassing ops served at the coherence
// point -> no L2 wb/inv fences needed anywhere.
__device__ __forceinline__ float agent_load(const float* p) {
    return __hip_atomic_load(p, __ATOMIC_RELAXED, __HIP_MEMORY_SCOPE_AGENT);
}
__device__ __forceinline__ void agent_store(float* p, float v) {
    __hip_atomic_store(p, v, __ATOMIC_RELAXED, __HIP_MEMORY_SCOPE_AGENT);
}
__device__ __forceinline__ unsigned flag_load(const unsigned* p) {
    return __hip_atomic_load(p, __ATOMIC_RELAXED, __HIP_MEMORY_SCOPE_AGENT);
}
__device__ __forceinline__ void flag_store(unsigned* p, unsigned v) {
    __hip_atomic_store(p, v, __ATOMIC_RELAXED, __HIP_MEMORY_SCOPE_AGENT);
}
__device__ __forceinline__ void flag_bump(unsigned* p) {
    (void)__hip_atomic_fetch_add(p, 1u, __ATOMIC_RELAXED,
                                 __HIP_MEMORY_SCOPE_AGENT);
}
__device__ __forceinline__ float agent_fadd(float* p, float v) {
    return __hip_atomic_fetch_add(p, v, __ATOMIC_RELAXED, __HIP_MEMORY_SCOPE_AGENT);
}

// Block barrier waiting ONLY on LDS ops (lgkmcnt): global prefetch loads
// stay in flight across it (__syncthreads would drain vmcnt(0)).
__device__ __forceinline__ void lds_barrier() {
    asm volatile("s_waitcnt lgkmcnt(0)\n\ts_barrier" ::: "memory");
}

// Hierarchical grid barrier with an OFF-CRITICAL-PATH leader (block 62,
// otherwise idle). Entry __syncthreads drains this block's stores/atomics
// (vmcnt 0) before the arrival flag.
#define BAR_LEADER 62
__device__ __forceinline__ void grid_barrier(int blk, unsigned phase) {
    __syncthreads();
    if (blk == BAR_LEADER) {
        if (threadIdx.x < 64 && threadIdx.x != BAR_LEADER) {
            while (flag_load(&g_arrive[threadIdx.x * 16]) < phase)
                __builtin_amdgcn_s_sleep(1);
        }
        __syncthreads();   // all lanes saw their arrival
        if (threadIdx.x == 0) flag_store(&g_go, phase);
    } else {
        if (threadIdx.x == 0) {
            flag_store(&g_arrive[blk * 16], phase);
            while (flag_load(&g_go) < phase)
                __builtin_amdgcn_s_sleep(1);
        }
    }
    __syncthreads();
}

// Single launch, 64 blocks x 512 threads, role-split:
//   blocks 0-20 : GCN (own row) + FC1 rows [21b, 21b+21)   (fan-in 21)
//   blocks 21-36: FC2 rows [32(b-21), +32)                 (fan-in 16)
//   blocks 37-44: FC3 COLUMN-OWNED: cols [32(b-37), +32), full K=512,
//                 direct out write (no acc3, no finale round trip)
//   block 62    : barrier leader + g_go/g_seen reset
//   block 63    : zeroes acc1/acc2, sets g_zr (resets it after bar1)
// Barriers: FC1 -> bar(1) -> FC2 -> bar(2) -> FC3 -> out (direct).
__global__ __launch_bounds__(512) void fused_kernel(
    const float* __restrict__ state,      // [B,21,128], only batch 0 used
    const int*   __restrict__ edge_index, // [2,128]
    const float* __restrict__ W1,         // [128,21]
    const float* __restrict__ b1,         // [21]
    const float* __restrict__ W2,         // [21,21]
    const float* __restrict__ b2,         // [21]
    const float* __restrict__ Wf1,        // [441,512]
    const float* __restrict__ bf1,        // [512]
    const float* __restrict__ Wf2,        // [512,512]
    const float* __restrict__ bf2,        // [512]
    const float* __restrict__ Wf3,        // [512,256]
    const float* __restrict__ bf3,        // [256]
    float* __restrict__ ws,
    float* __restrict__ out)
{
    const int b = blockIdx.x;
    const int t = threadIdx.x;

    const bool is_gcn = (b < 21);                 // also the FC1 blocks
    const bool do_fc2 = (b >= 21 && b < 37);
    const bool do_fc3 = (b >= 37 && b < 45);

    // ---------------- LDS ----------------
    __shared__ float sA[21 * APAD];
    __shared__ float sX[21 * W1PAD];
    __shared__ float sW1T[21 * W1PAD];
    __shared__ float sW2T[21 * APAD];
    __shared__ float sT[21 * APAD];      // h1T then h2T
    __shared__ float sG[21 * APAD];      // g1
    __shared__ float sv[441];
    __shared__ float sdeg[21];
    __shared__ float sb1[21], sb2[21];
    __shared__ float x1s[32];
    __shared__ float x2s[512];
    __shared__ float pt[32 * 16];        // FC3 partials [col][jg]

    // ---------------- role prefetches (coalesced reads) ----------------
    float wf1v[21];
    if (is_gcn) {
        #pragma unroll
        for (int i = 0; i < 21; ++i) wf1v[i] = Wf1[(size_t)(21 * b + i) * 512 + t];
    }
    float wf2v[32];
    float rbf1 = 0.0f;
    if (do_fc2) {
        #pragma unroll
        for (int i = 0; i < 32; ++i) wf2v[i] = Wf2[(size_t)(32 * (b - 21) + i) * 512 + t];
        if (t < 32) rbf1 = bf1[32 * (b - 21) + t];
    }
    // FC3 column-owned: thread t = jg*32 + cl covers rows [32jg, 32jg+32)
    // of column c0+cl. Per wave-instr: 2x 128B row segments (coalesced).
    const int jg = t >> 5, cl = t & 31;
    const int c0 = 32 * (b - 37);
    float wf3v[32];
    float rbf2 = 0.0f, rbf3r = 0.0f;
    if (do_fc3) {
        #pragma unroll
        for (int jj = 0; jj < 32; ++jj)
            wf3v[jj] = Wf3[(size_t)(32 * jg + jj) * 256 + c0 + cl];
        rbf2 = bf2[t];
        if (t < 32) rbf3r = bf3[c0 + t];
    }

    // ---------------- zeroer: block 63 ----------------
    if (b == 63) {
        agent_store(&ws[WS_ACC1 + t], 0.0f);
        agent_store(&ws[WS_ACC2 + t], 0.0f);
        __syncthreads();                          // drain zero stores (vmcnt 0)
        if (t == 0) flag_store(&g_zr, 1u);        // zeros globally visible
    }

    // ---------------- GCN: blocks 0..20 only ----------------
    if (is_gcn) {
        // P0: zero pads, stage X/W1T/W2T, edges
        for (int i = t; i < 21 * APAD; i += 512) {
            sA[i] = 0.0f; sW2T[i] = 0.0f; sT[i] = 0.0f; sG[i] = 0.0f;
        }
        if (t < 21) { sdeg[t] = 1.0f; sb1[t] = b1[t]; sb2[t] = b2[t]; }
        {
            const float4* src4 = (const float4*)state;      // batch 0
            for (int i = t; i < 672; i += 512) {            // 21*128/4
                int n = i >> 5, fc = i & 31;
                ((float4*)&sX[n * W1PAD])[fc] = src4[i];
            }
        }
        for (int i = t; i < 2688; i += 512) {               // W1 -> sW1T[k][f]
            int f = i / 21, k = i - f * 21;
            sW1T[k * W1PAD + f] = W1[i];
        }
        for (int i = t; i < 441; i += 512) {                // W2 -> sW2T[k][f]
            int f = i / 21, k = i - f * 21;
            sW2T[k * APAD + f] = W2[i];
        }
        int er = 0, ec = 0;
        if (t < 128) { er = edge_index[t]; ec = edge_index[128 + t]; }
        lds_barrier();

        // P1: adjacency scatter (+deg, +self-loop)  ||  h1 = X @ W1
        if (t < 128) {
            atomicAdd(&sA[er * APAD + ec], 1.0f);
            atomicAdd(&sdeg[ec], 1.0f);
        }
        if (t < 21) atomicAdd(&sA[t * APAD + t], 1.0f);
        if (t < 441) {
            int n = t / 21, k = t - n * 21;
            const float4* x4 = (const float4*)&sX[n * W1PAD];
            const float4* w4 = (const float4*)&sW1T[k * W1PAD];
            float s = 0.0f;
            #pragma unroll
            for (int fc = 0; fc < 32; ++fc) {
                float4 a = x4[fc], ww = w4[fc];
                s += a.x * ww.x; s += a.y * ww.y; s += a.z * ww.z; s += a.w * ww.w;
            }
            sT[k * APAD + n] = s;
        }
        lds_barrier();

        // P2: normalize A
        if (t < 441) {
            int r = t / 21, c = t - r * 21;
            float dr = 1.0f / sqrtf(sdeg[r]);
            float dc = 1.0f / sqrtf(sdeg[c]);
            sA[r * APAD + c] = dr * sA[r * APAD + c] * dc;
        }
        lds_barrier();

        // P3: g1[i,k] = b1[k] + A[i,:] . h1T[k,:]
        if (t < 441) {
            int r = t / 21, k = t - r * 21;
            const float4* a4 = (const float4*)&sA[r * APAD];
            const float4* h4 = (const float4*)&sT[k * APAD];
            float s = sb1[k];
            #pragma unroll
            for (int jc = 0; jc < 6; ++jc) {
                float4 a = a4[jc], h = h4[jc];
                s += a.x * h.x; s += a.y * h.y; s += a.z * h.z; s += a.w * h.w;
            }
            sG[r * APAD + k] = s;
        }
        lds_barrier();

        // P4: h2[n,k] = g1[n,:] . W2T[k,:]
        if (t < 441) {
            int n = t / 21, k = t - n * 21;
            const float4* g4 = (const float4*)&sG[n * APAD];
            const float4* w4 = (const float4*)&sW2T[k * APAD];
            float s = 0.0f;
            #pragma unroll
            for (int jc = 0; jc < 6; ++jc) {
                float4 g = g4[jc], ww = w4[jc];
                s += g.x * ww.x; s += g.y * ww.y; s += g.z * ww.z; s += g.w * ww.w;
            }
            sT[k * APAD + n] = s;
        }
        lds_barrier();

        // P5: v[i*21+k] = b2[k] + A[i,:] . h2T[k,:]
        // Gate folded in: lane 448 (idle during P5) polls g_zr concurrently.
        if (t < 441) {
            int r = t / 21, k = t - r * 21;
            const float4* a4 = (const float4*)&sA[r * APAD];
            const float4* h4 = (const float4*)&sT[k * APAD];
            float s = sb2[k];
            #pragma unroll
            for (int jc = 0; jc < 6; ++jc) {
                float4 a = a4[jc], h = h4[jc];
                s += a.x * h.x; s += a.y * h.y; s += a.z * h.z; s += a.w * h.w;
            }
            sv[t] = s;
        }
        if (t == 448) {
            while (flag_load(&g_zr) == 0u) __builtin_amdgcn_s_sleep(1);
        }
        lds_barrier();

        // FC1 (row-split): rows [21b, 21b+21)
        {
            float s = 0.0f;
            #pragma unroll
            for (int r = 0; r < 21; ++r) s += sv[21 * b + r] * wf1v[r];
            agent_fadd(&ws[WS_ACC1 + t], s);
        }
    }

    grid_barrier(b, 1);   // acc1 complete (and acc2 zeros via block 63)

    // g_zr reset: bar1 release proves all GCN blocks passed the gate.
    if (b == 63 && t == 0) flag_store(&g_zr, 0u);

    // ---------------- FC2: blocks 21..36, rows [32(b-21), +32) -------------
    if (do_fc2) {
        if (t < 32)
            x1s[t] = fmaxf(agent_load(&ws[WS_ACC1 + 32 * (b - 21) + t]) + rbf1, 0.0f);
        lds_barrier();
        float s = 0.0f;
        #pragma unroll
        for (int j = 0; j < 32; ++j) s += x1s[j] * wf2v[j];
        agent_fadd(&ws[WS_ACC2 + t], s);
    }

    grid_barrier(b, 2);   // acc2 complete

    // Post-bar2 bookkeeping (off the output critical path):
    //   non-leader blocks: self-reset arrival slot, confirm via g_seen.
    //   leader: collect 63 confirmations, reset g_go/g_seen, exit — this
    //   completes while FC3 blocks still compute, adding zero duration.
    if (b != BAR_LEADER) {
        if (t == 0) {
            flag_store(&g_arrive[b * 16], 0u);
            flag_bump(&g_seen);
        }
    } else {
        if (t == 0) {
            while (flag_load(&g_seen) < 63u) __builtin_amdgcn_s_sleep(1);
            flag_store(&g_go, 0u);
            flag_store(&g_seen, 0u);
        }
    }

    // ---------------- FC3: blocks 37..44, COLUMN-OWNED, direct out ---------
    if (do_fc3) {
        x2s[t] = fmaxf(agent_load(&ws[WS_ACC2 + t]) + rbf2, 0.0f);
        lds_barrier();
        {
            float s = 0.0f;
            #pragma unroll
            for (int jj = 0; jj < 32; ++jj) s += x2s[32 * jg + jj] * wf3v[jj];
            pt[cl * 16 + jg] = s;
        }
        lds_barrier();
        if (t < 32) {
            float s = 0.0f;
            #pragma unroll
            for (int g = 0; g < 16; ++g) s += pt[t * 16 + g];
            out[c0 + t] = fmaxf(s + rbf3r, 0.0f);
        }
    }
}

extern "C" void kernel_launch(void* const* d_in, const int* in_sizes, int n_in,
                              void* d_out, int out_size, void* d_ws, size_t ws_size,
                              hipStream_t stream)
{
    const float* state      = (const float*)d_in[0];
    const int*   edge_index = (const int*)  d_in[1];
    const float* W1  = (const float*)d_in[2];
    const float* b1  = (const float*)d_in[3];
    const float* W2  = (const float*)d_in[4];
    const float* b2  = (const float*)d_in[5];
    const float* Wf1 = (const float*)d_in[6];
    const float* bf1 = (const float*)d_in[7];
    const float* Wf2 = (const float*)d_in[8];
    const float* bf2 = (const float*)d_in[9];
    const float* Wf3 = (const float*)d_in[10];
    const float* bf3 = (const float*)d_in[11];

    float* ws  = (float*)d_ws;
    float* out = (float*)d_out;

    fused_kernel<<<64, 512, 0, stream>>>(state, edge_index, W1, b1, W2, b2,
                                         Wf1, bf1, Wf2, bf2, Wf3, bf3, ws, out);
}

// Round 17
// 15.428 us; speedup vs baseline: 1.0169x; 1.0169x over previous
//
#include <hip/hip_runtime.h>
#include <math.h>

#define APAD 28          // padded row stride for 21-wide tiles
#define W1PAD 132        // padded row stride for 128-wide tiles

// ws float layout (acc zeroed by block 63 each launch; poison-safe):
#define WS_ACC1 0
#define WS_ACC2 512
#define WS_ACC3 1024

// Reset-based sync state: all words are 0 at module load, and the finalizer
// block restores every word to 0 before kernel end (stream ordering + the
// end-of-dispatch release fence make this visible to the next launch).
__device__ unsigned g_arrive[64 * 16];   // 64B-strided arrival slots
__device__ unsigned g_go;                // barrier release word
__device__ unsigned g_zr;                // accumulators-zeroed flag
__device__ unsigned g_cnt;               // finale completion counter

// Agent-scope relaxed atomics: cache-bypassing ops served at the coherence
// point -> no L2 wb/inv fences needed anywhere.
__device__ __forceinline__ float agent_load(const float* p) {
    return __hip_atomic_load(p, __ATOMIC_RELAXED, __HIP_MEMORY_SCOPE_AGENT);
}
__device__ __forceinline__ void agent_store(float* p, float v) {
    __hip_atomic_store(p, v, __ATOMIC_RELAXED, __HIP_MEMORY_SCOPE_AGENT);
}
__device__ __forceinline__ unsigned flag_load(const unsigned* p) {
    return __hip_atomic_load(p, __ATOMIC_RELAXED, __HIP_MEMORY_SCOPE_AGENT);
}
__device__ __forceinline__ void flag_store(unsigned* p, unsigned v) {
    __hip_atomic_store(p, v, __ATOMIC_RELAXED, __HIP_MEMORY_SCOPE_AGENT);
}
__device__ __forceinline__ float agent_fadd(float* p, float v) {
    return __hip_atomic_fetch_add(p, v, __ATOMIC_RELAXED, __HIP_MEMORY_SCOPE_AGENT);
}

// Block barrier waiting ONLY on LDS ops (lgkmcnt): global prefetch loads
// stay in flight across it (__syncthreads would drain vmcnt(0)).
__device__ __forceinline__ void lds_barrier() {
    asm volatile("s_waitcnt lgkmcnt(0)\n\ts_barrier" ::: "memory");
}

// Hierarchical grid barrier with an OFF-CRITICAL-PATH leader (block 62,
// otherwise idle): it polls arrivals while workers still compute and
// releases immediately when the last worker arrives. Entry __syncthreads
// drains this block's stores/atomics (vmcnt 0) before the arrival flag.
#define BAR_LEADER 62
__device__ __forceinline__ void grid_barrier(int blk, unsigned phase) {
    __syncthreads();
    if (blk == BAR_LEADER) {
        if (threadIdx.x < 64 && threadIdx.x != BAR_LEADER) {
            while (flag_load(&g_arrive[threadIdx.x * 16]) < phase)
                __builtin_amdgcn_s_sleep(1);
        }
        __syncthreads();   // all lanes saw their arrival
        if (threadIdx.x == 0) flag_store(&g_go, phase);
    } else {
        if (threadIdx.x == 0) {
            flag_store(&g_arrive[blk * 16], phase);
            while (flag_load(&g_go) < phase)
                __builtin_amdgcn_s_sleep(1);
        }
    }
    __syncthreads();
}

// Single launch, 64 blocks x 512 threads, role-split:
//   blocks 0-20 : GCN (own row) + FC1 rows [21b, 21b+21)   (fan-in 21)
//   blocks 21-36: FC2 rows [32(b-21), +32)                 (fan-in 16)
//   blocks 37-44: FC3 rows [64(b-37), +64)                 (fan-in 8)
//   block 62    : barrier leader (idle otherwise; polls off-critical-path)
//   block 63    : zeroes acc1/acc2/acc3, sets g_zr
// Barriers: FC1 -> bar(1) -> FC2 -> bar(2) -> FC3 -> completion-count finale.
// The g_zr gate is folded INTO the P5 phase (lane 448 polls while 21 threads
// compute v) -> one lds_barrier covers both, removing 2 syncs vs round 14.
__global__ __launch_bounds__(512) void fused_kernel(
    const float* __restrict__ state,      // [B,21,128], only batch 0 used
    const int*   __restrict__ edge_index, // [2,128]
    const float* __restrict__ W1,         // [128,21]
    const float* __restrict__ b1,         // [21]
    const float* __restrict__ W2,         // [21,21]
    const float* __restrict__ b2,         // [21]
    const float* __restrict__ Wf1,        // [441,512]
    const float* __restrict__ bf1,        // [512]
    const float* __restrict__ Wf2,        // [512,512]
    const float* __restrict__ bf2,        // [512]
    const float* __restrict__ Wf3,        // [512,256]
    const float* __restrict__ bf3,        // [256]
    float* __restrict__ ws,
    float* __restrict__ out)
{
    const int b = blockIdx.x;
    const int t = threadIdx.x;

    const bool is_gcn = (b < 21);                 // also the FC1 blocks
    const bool do_fc2 = (b >= 21 && b < 37);
    const bool do_fc3 = (b >= 37 && b < 45);

    // ---------------- LDS ----------------
    __shared__ float sA[21 * APAD];
    __shared__ float sX[21 * W1PAD];
    __shared__ float sW1T[21 * W1PAD];
    __shared__ float sW2T[21 * APAD];
    __shared__ float sT[21 * APAD];      // h1T then h2T
    __shared__ float sG[21 * APAD];      // g1
    __shared__ float sv[441];
    __shared__ float sdeg[21];
    __shared__ float sb1[21], sb2[21];
    __shared__ float x1s[32], x2s[64];
    __shared__ unsigned sflag;

    // ---------------- role prefetches (coalesced row reads) ----------------
    float wf1v[21];
    if (is_gcn) {
        #pragma unroll
        for (int i = 0; i < 21; ++i) wf1v[i] = Wf1[(size_t)(21 * b + i) * 512 + t];
    }
    float wf2v[32];
    float rbf1 = 0.0f;
    if (do_fc2) {
        #pragma unroll
        for (int i = 0; i < 32; ++i) wf2v[i] = Wf2[(size_t)(32 * (b - 21) + i) * 512 + t];
        if (t < 32) rbf1 = bf1[32 * (b - 21) + t];
    }
    float wf3v[64];
    float rbf2 = 0.0f;
    if (do_fc3) {
        if (t < 256) {
            #pragma unroll
            for (int i = 0; i < 64; ++i) wf3v[i] = Wf3[(size_t)(64 * (b - 37) + i) * 256 + t];
        }
        if (t < 64) rbf2 = bf2[64 * (b - 37) + t];
    }
    const float rbf3 = bf3[t & 255];   // any block may finalize

    // ---------------- zeroer: block 63 ----------------
    if (b == 63) {
        agent_store(&ws[WS_ACC1 + t], 0.0f);
        agent_store(&ws[WS_ACC2 + t], 0.0f);
        if (t < 256) agent_store(&ws[WS_ACC3 + t], 0.0f);
        __syncthreads();                          // drain zero stores (vmcnt 0)
        if (t == 0) flag_store(&g_zr, 1u);        // zeros globally visible
    }

    // ---------------- GCN: blocks 0..20 only ----------------
    if (is_gcn) {
        // P0: zero pads, stage X/W1T/W2T, edges
        for (int i = t; i < 21 * APAD; i += 512) {
            sA[i] = 0.0f; sW2T[i] = 0.0f; sT[i] = 0.0f; sG[i] = 0.0f;
        }
        if (t < 21) { sdeg[t] = 1.0f; sb1[t] = b1[t]; sb2[t] = b2[t]; }
        {
            const float4* src4 = (const float4*)state;      // batch 0
            for (int i = t; i < 672; i += 512) {            // 21*128/4
                int n = i >> 5, fc = i & 31;
                ((float4*)&sX[n * W1PAD])[fc] = src4[i];
            }
        }
        for (int i = t; i < 2688; i += 512) {               // W1 -> sW1T[k][f]
            int f = i / 21, k = i - f * 21;
            sW1T[k * W1PAD + f] = W1[i];
        }
        for (int i = t; i < 441; i += 512) {                // W2 -> sW2T[k][f]
            int f = i / 21, k = i - f * 21;
            sW2T[k * APAD + f] = W2[i];
        }
        int er = 0, ec = 0;
        if (t < 128) { er = edge_index[t]; ec = edge_index[128 + t]; }
        lds_barrier();

        // P1: adjacency scatter (+deg, +self-loop)  ||  h1 = X @ W1
        if (t < 128) {
            atomicAdd(&sA[er * APAD + ec], 1.0f);
            atomicAdd(&sdeg[ec], 1.0f);
        }
        if (t < 21) atomicAdd(&sA[t * APAD + t], 1.0f);
        if (t < 441) {
            int n = t / 21, k = t - n * 21;
            const float4* x4 = (const float4*)&sX[n * W1PAD];
            const float4* w4 = (const float4*)&sW1T[k * W1PAD];
            float s = 0.0f;
            #pragma unroll
            for (int fc = 0; fc < 32; ++fc) {
                float4 a = x4[fc], ww = w4[fc];
                s += a.x * ww.x; s += a.y * ww.y; s += a.z * ww.z; s += a.w * ww.w;
            }
            sT[k * APAD + n] = s;
        }
        lds_barrier();

        // P2: normalize A
        if (t < 441) {
            int r = t / 21, c = t - r * 21;
            float dr = 1.0f / sqrtf(sdeg[r]);
            float dc = 1.0f / sqrtf(sdeg[c]);
            sA[r * APAD + c] = dr * sA[r * APAD + c] * dc;
        }
        lds_barrier();

        // P3: g1[i,k] = b1[k] + A[i,:] . h1T[k,:]
        if (t < 441) {
            int r = t / 21, k = t - r * 21;
            const float4* a4 = (const float4*)&sA[r * APAD];
            const float4* h4 = (const float4*)&sT[k * APAD];
            float s = sb1[k];
            #pragma unroll
            for (int jc = 0; jc < 6; ++jc) {
                float4 a = a4[jc], h = h4[jc];
                s += a.x * h.x; s += a.y * h.y; s += a.z * h.z; s += a.w * h.w;
            }
            sG[r * APAD + k] = s;
        }
        lds_barrier();

        // P4: h2[n,k] = g1[n,:] . W2T[k,:]
        if (t < 441) {
            int n = t / 21, k = t - n * 21;
            const float4* g4 = (const float4*)&sG[n * APAD];
            const float4* w4 = (const float4*)&sW2T[k * APAD];
            float s = 0.0f;
            #pragma unroll
            for (int jc = 0; jc < 6; ++jc) {
                float4 g = g4[jc], ww = w4[jc];
                s += g.x * ww.x; s += g.y * ww.y; s += g.z * ww.z; s += g.w * ww.w;
            }
            sT[k * APAD + n] = s;
        }
        lds_barrier();

        // P5: v[i*21+k] = b2[k] + A[i,:] . h2T[k,:]
        // Gate folded in: lane 448 (idle during P5) polls g_zr concurrently;
        // the single lds_barrier below orders BOTH sv writes and the gate
        // before the FC1 adds (zero serial sync cost).
        if (t < 441) {
            int r = t / 21, k = t - r * 21;
            const float4* a4 = (const float4*)&sA[r * APAD];
            const float4* h4 = (const float4*)&sT[k * APAD];
            float s = sb2[k];
            #pragma unroll
            for (int jc = 0; jc < 6; ++jc) {
                float4 a = a4[jc], h = h4[jc];
                s += a.x * h.x; s += a.y * h.y; s += a.z * h.z; s += a.w * h.w;
            }
            sv[t] = s;
        }
        if (t == 448) {
            while (flag_load(&g_zr) == 0u) __builtin_amdgcn_s_sleep(1);
        }
        lds_barrier();

        // FC1 (row-split): rows [21b, 21b+21)
        {
            float s = 0.0f;
            #pragma unroll
            for (int r = 0; r < 21; ++r) s += sv[21 * b + r] * wf1v[r];
            agent_fadd(&ws[WS_ACC1 + t], s);
        }
    }

    grid_barrier(b, 1);   // acc1 complete (and acc2/acc3 zeros via block 63)

    // ---------------- FC2: blocks 21..36, rows [32(b-21), +32) -------------
    if (do_fc2) {
        if (t < 32)
            x1s[t] = fmaxf(agent_load(&ws[WS_ACC1 + 32 * (b - 21) + t]) + rbf1, 0.0f);
        lds_barrier();
        float s = 0.0f;
        #pragma unroll
        for (int j = 0; j < 32; ++j) s += x1s[j] * wf2v[j];
        agent_fadd(&ws[WS_ACC2 + t], s);
    }

    grid_barrier(b, 2);   // acc2 complete

    // ---------------- FC3: blocks 37..44, rows [64(b-37), +64) -------------
    if (do_fc3) {
        if (t < 64)
            x2s[t] = fmaxf(agent_load(&ws[WS_ACC2 + 64 * (b - 37) + t]) + rbf2, 0.0f);
        lds_barrier();
        if (t < 256) {
            float s = 0.0f;
            #pragma unroll
            for (int j = 0; j < 64; ++j) s += x2s[j] * wf3v[j];
            agent_fadd(&ws[WS_ACC3 + t], s);
        }
    }

    // ---------------- finale: completion count; 64th block finalizes -------
    __syncthreads();                        // drain this block's FC3 adds
    if (t == 0) {
        unsigned prev = __hip_atomic_fetch_add(&g_cnt, 1u, __ATOMIC_RELAXED,
                                               __HIP_MEMORY_SCOPE_AGENT);
        sflag = (prev == 63u) ? 1u : 0u;
    }
    __syncthreads();
    if (sflag) {
        if (t < 256) {
            float a = agent_load(&ws[WS_ACC3 + t]) + rbf3;
            out[t] = fmaxf(a, 0.0f);
        }
        // Restore ALL sync words to 0 for the next launch (all uses in this
        // launch happen-before the 64th g_cnt increment; end-of-dispatch
        // release publishes the resets before the next launch starts).
        if (t >= 256 && t < 320) flag_store(&g_arrive[(t - 256) * 16], 0u);
        if (t == 320) flag_store(&g_go, 0u);
        if (t == 321) flag_store(&g_zr, 0u);
        if (t == 322) flag_store(&g_cnt, 0u);
    }
}

extern "C" void kernel_launch(void* const* d_in, const int* in_sizes, int n_in,
                              void* d_out, int out_size, void* d_ws, size_t ws_size,
                              hipStream_t stream)
{
    const float* state      = (const float*)d_in[0];
    const int*   edge_index = (const int*)  d_in[1];
    const float* W1  = (const float*)d_in[2];
    const float* b1  = (const float*)d_in[3];
    const float* W2  = (const float*)d_in[4];
    const float* b2  = (const float*)d_in[5];
    const float* Wf1 = (const float*)d_in[6];
    const float* bf1 = (const float*)d_in[7];
    const float* Wf2 = (const float*)d_in[8];
    const float* bf2 = (const float*)d_in[9];
    const float* Wf3 = (const float*)d_in[10];
    const float* bf3 = (const float*)d_in[11];

    float* ws  = (float*)d_ws;
    float* out = (float*)d_out;

    fused_kernel<<<64, 512, 0, stream>>>(state, edge_index, W1, b1, W2, b2,
                                         Wf1, bf1, Wf2, bf2, Wf3, bf3, ws, out);
}